// Round 1
// baseline (584.140 us; speedup 1.0000x reference)
//
#include <hip/hip_runtime.h>

// Windowed cross-correlation cost volume (FlowNet-C), MI355X fp32 vector kernel.
// out[n, d, y, x] = (1/C) * sum_c in1[n,c,y,x] * in2pad[n,c,y+dy,x+dx]
// N=8 C=256 H=64 W=128, disp in [-4,4]^2 -> 81 channels.

#define NN 8
#define CC 256
#define HH 64
#define WW 128
#define MD 4          // max displacement
#define TH 16         // tile rows
#define TW 32         // tile cols
#define XGN 4         // x-groups per tile (TW/8)
#define CS 2          // channel split (grid filler)
#define CPB (CC/CS)   // 128 channels per block
#define CB 4          // channels staged per stage
#define NST (CPB/CB)  // 32 stages
#define S2 52         // in2 LDS row stride (floats); 40 valid. 52 -> uniform 8/bank
#define R2 (TH+2*MD)  // 24 in2 rows
#define S1 36         // in1 LDS row stride; 32 valid. 36 -> uniform 8/bank
#define R1 TH         // 16 in1 rows
#define CH2 (R2*S2)   // 1248 floats / channel (1248 % 32 == 0)
#define CH1 (R1*S1)   // 576 floats / channel  (576 % 32 == 0)
#define BUF2 (CB*CH2) // 4992
#define BUF1 (CB*CH1) // 2304
#define SLOTS2 (CB*R2*10)   // 960 float4 slots per stage (in2)
#define SLOTS1 (CB*R1*8)    // 512 float4 slots per stage (in1)
#define NSLOT (SLOTS2+SLOTS1) // 1472
#define NT 576        // 9 waves: wave w <-> dyIdx w

__global__ __launch_bounds__(NT, 2) void corr_cost_volume(
    const float* __restrict__ in1, const float* __restrict__ in2,
    float* __restrict__ out)
{
    __shared__ float lds2[2][BUF2];
    __shared__ float lds1[2][BUF1];

    const int tid  = threadIdx.x;
    const int dyI  = tid >> 6;        // 0..8  (wave index = dy+4)
    const int lane = tid & 63;
    const int yy   = lane >> 2;       // 0..15 (row within tile)
    const int xg   = lane & 3;        // 0..3  (8-pixel group)

    const int b  = blockIdx.x;
    const int cs = b & 1;
    const int xt = (b >> 1) & 3;
    const int yt = (b >> 3) & 3;
    const int n  = b >> 5;            // 0..7
    const int x0 = xt * TW;
    const int y0 = yt * TH;
    const int c0 = cs * CPB;

    // ---------------- staging slot setup (2..3 float4 slots per thread) ----
    // slot q in [0,960): in2: ch=q/240, r=(q%240)/10, s=q%10
    //        q in [960,1472): in1: q1=q-960: ch=q1/128, r=(q1%128)/8, s=q1%8
    const float4* gp[3];
    float* dstA[3];          // LDS dest, buffer 0
    int dstDelta[3];         // add for buffer 1
    int vld[3];
    const int nslots = (tid < (NSLOT - 2 * NT)) ? 3 : 2;   // tid<320 -> 3

    for (int k = 0; k < 3; ++k) {
        int q = tid + k * NT;
        if (q >= NSLOT) { gp[k] = (const float4*)in1; dstA[k] = &lds1[0][0];
                          dstDelta[k] = BUF1; vld[k] = 0; continue; }
        int ch, gy, gx, lOff, isI2;
        if (q < SLOTS2) {
            isI2 = 1;
            ch = q / 240; int rem = q - ch * 240;
            int r = rem / 10; int s = rem - r * 10;
            gy = y0 - MD + r; gx = x0 - MD + 4 * s;
            lOff = ch * CH2 + r * S2 + 4 * s;
        } else {
            isI2 = 0;
            int q1 = q - SLOTS2;
            ch = q1 >> 7; int rem = q1 & 127;
            int r = rem >> 3; int s = rem & 7;
            gy = y0 + r; gx = x0 + 4 * s;
            lOff = ch * CH1 + r * S1 + 4 * s;
        }
        const int ok = ((unsigned)gy < HH) && ((unsigned)gx < WW);
        const float* src = isI2 ? in2 : in1;
        long goff = (((long)(n * CC + c0 + ch)) * HH + (ok ? gy : 0)) * WW + (ok ? gx : 0);
        gp[k] = (const float4*)(src + goff);
        dstA[k] = isI2 ? &lds2[0][lOff] : &lds1[0][lOff];
        dstDelta[k] = isI2 ? BUF2 : BUF1;
        vld[k] = ok;
    }
    const int gAdv = CB * HH * WW / 4;   // float4 advance per stage

    // ---------------- per-thread compute offsets ----------------
    const int off2 = (yy + dyI) * S2 + 8 * xg;   // window row y+dy, cols 8xg..8xg+15
    const int off1 = yy * S1 + 8 * xg;

    float acc[9][8];
#pragma unroll
    for (int d = 0; d < 9; ++d)
#pragma unroll
        for (int p = 0; p < 8; ++p) acc[d][p] = 0.0f;

    // ---------------- prologue: stage 0 into buffer 0 ----------------
    {
        float4 pv[3];
#pragma unroll
        for (int k = 0; k < 3; ++k) {
            if (k < nslots) {
                float4 t = *gp[k];
                pv[k] = vld[k] ? t : make_float4(0.f, 0.f, 0.f, 0.f);
                gp[k] += gAdv;
            }
        }
#pragma unroll
        for (int k = 0; k < 3; ++k)
            if (k < nslots) *(float4*)dstA[k] = pv[k];
        __syncthreads();
    }

    // ---------------- main loop ----------------
    int cur = 0;
    for (int st = 0; st < NST; ++st) {
        const bool pf = (st + 1 < NST);
        float4 pv[3];
        if (pf) {
#pragma unroll
            for (int k = 0; k < 3; ++k) {
                if (k < nslots) {
                    float4 t = *gp[k];
                    pv[k] = vld[k] ? t : make_float4(0.f, 0.f, 0.f, 0.f);
                    gp[k] += gAdv;
                }
            }
        }

        const float* L2 = lds2[cur];
        const float* L1 = lds1[cur];
#pragma unroll
        for (int ch = 0; ch < CB; ++ch) {
            const float4 a0 = *(const float4*)&L1[ch * CH1 + off1];
            const float4 a1 = *(const float4*)&L1[ch * CH1 + off1 + 4];
            const float4 w0 = *(const float4*)&L2[ch * CH2 + off2];
            const float4 w1 = *(const float4*)&L2[ch * CH2 + off2 + 4];
            const float4 w2 = *(const float4*)&L2[ch * CH2 + off2 + 8];
            const float4 w3 = *(const float4*)&L2[ch * CH2 + off2 + 12];
            const float a[8] = {a0.x, a0.y, a0.z, a0.w, a1.x, a1.y, a1.z, a1.w};
            const float w[16] = {w0.x, w0.y, w0.z, w0.w, w1.x, w1.y, w1.z, w1.w,
                                 w2.x, w2.y, w2.z, w2.w, w3.x, w3.y, w3.z, w3.w};
#pragma unroll
            for (int dx = 0; dx < 9; ++dx)
#pragma unroll
                for (int p = 0; p < 8; ++p)
                    acc[dx][p] = fmaf(a[p], w[p + dx], acc[dx][p]);
        }

        if (pf) {
            const int nxt = cur ^ 1;
#pragma unroll
            for (int k = 0; k < 3; ++k)
                if (k < nslots) *(float4*)(dstA[k] + (nxt ? dstDelta[k] : 0)) = pv[k];
            __syncthreads();
        }
        cur ^= 1;
    }

    // ---------------- epilogue: scaled atomic accumulate ----------------
    const float sc = 1.0f / (float)CC;
    const int xb = x0 + 8 * xg;
    const int yo = y0 + yy;
#pragma unroll
    for (int dx = 0; dx < 9; ++dx) {
        const int d = dyI * 9 + dx;
        float* op = out + (((long)n * 81 + d) * HH + yo) * WW + xb;
#pragma unroll
        for (int p = 0; p < 8; ++p)
            atomicAdd(op + p, acc[dx][p] * sc);
    }
}

extern "C" void kernel_launch(void* const* d_in, const int* in_sizes, int n_in,
                              void* d_out, int out_size, void* d_ws, size_t ws_size,
                              hipStream_t stream) {
    const float* in1 = (const float*)d_in[0];
    const float* in2 = (const float*)d_in[1];
    float* out = (float*)d_out;
    hipMemsetAsync(d_out, 0, (size_t)out_size * sizeof(float), stream);
    corr_cost_volume<<<dim3(NN * 4 * 4 * CS), dim3(NT), 0, stream>>>(in1, in2, out);
}

// Round 3
// 526.624 us; speedup vs baseline: 1.1092x; 1.1092x over previous
//
#include <hip/hip_runtime.h>

// FlowNet-C cost volume: out[n,d,y,x] = (1/C) * sum_c in1[n,c,y,x]*in2pad[n,c,y+dy,x+dx]
// N=8 C=256 H=64 W=128, d = (dy+4)*9+(dx+4), 81 channels.
//
// Design (round 2, resubmit after infra failure): TH=8 x TW=32 tile, 9 dy-waves
// (576 thr), 4 px/thread, acc[9][4]=36 VGPRs (round-1's 72 spilled at VGPR=84
// -> 500us scratch-bound). in2 halo tile staged in LDS (double-buffered, CB=8
// ch/stage, S2=44 pad -> conflict-free b128). in1 loaded direct from global
// (L1-shared across the 9 dy-waves), software-pipelined one stage ahead.
// No channel split -> no atomics (round-1 atomics wrote 592 MB vs 21 MB ideal).

#define NN 8
#define CC 256
#define HH 64
#define WW 128
#define HW (HH*WW)      // 8192
#define MD 4
#define TH 8
#define TW 32
#define CB 8            // channels per stage
#define NST (CC/CB)     // 32 stages
#define R2 (TH+2*MD)    // 16 in2 rows
#define S2 44           // in2 LDS row stride (floats); 40 valid; 44 -> uniform banks
#define CH2 (R2*S2)     // 704
#define BUF2 (CB*CH2)   // 5632 floats per buffer
#define SLOTS2 (CB*R2*10) // 1280 float4 staging slots per stage
#define NT 576          // 9 waves; wave w <-> dy index w

__global__ __launch_bounds__(NT)
__attribute__((amdgpu_waves_per_eu(2, 3)))
void corr_cost_volume(const float* __restrict__ in1,
                      const float* __restrict__ in2,
                      float* __restrict__ out)
{
    __shared__ float lds2[2][BUF2];   // 45 KB

    const int tid  = threadIdx.x;
    const int dyI  = tid >> 6;        // 0..8 (wave = dy+4)
    const int lane = tid & 63;
    const int yy   = lane >> 3;       // 0..7 row in tile
    const int xg   = lane & 7;        // 0..7 4-px group

    const int b  = blockIdx.x;        // grid = 4*8*8 = 256
    const int xt = b & 3;
    const int yt = (b >> 2) & 7;
    const int n  = b >> 5;
    const int x0 = xt * TW;
    const int y0 = yt * TH;

    // ---- staging slot setup: q = tid + k*NT, in2 only -------------------
    // slot q: ch=q/160, r=(q%160)/10, s=q%10 ; covers rows y0-4+r, cols x0-4+4s
    int sOff[3];   // element offset within (n, stage-base) cube
    int lOff[3];   // LDS float offset within one buffer
    int vld[3];
    const int nslots = (tid < (SLOTS2 - 2 * NT)) ? 3 : 2;   // tid<128 -> 3
#pragma unroll
    for (int k = 0; k < 3; ++k) {
        int q = tid + k * NT;
        if (q >= SLOTS2) { sOff[k] = 0; lOff[k] = 0; vld[k] = 0; continue; }
        int ch = q / 160;
        int rem = q - ch * 160;
        int r = rem / 10;
        int s = rem - r * 10;
        int gy = y0 - MD + r;
        int gx = x0 - MD + 4 * s;
        const int ok = ((unsigned)gy < HH) && ((unsigned)gx < WW);
        sOff[k] = (ch * HH + (ok ? gy : 0)) * WW + (ok ? gx : 0);
        lOff[k] = ch * CH2 + r * S2 + 4 * s;
        vld[k] = ok;
    }

    const float* b2p = in2 + (long)n * CC * HW;                     // stage ch base
    const float* b1p = in1 + (long)n * CC * HW + (y0 + yy) * WW + x0 + 4 * xg;

    const int off2 = (yy + dyI) * S2 + 4 * xg;   // in2 window base in LDS

    float acc[9][4];
#pragma unroll
    for (int d = 0; d < 9; ++d)
#pragma unroll
        for (int p = 0; p < 4; ++p) acc[d][p] = 0.0f;

    // ---- prologue: in1 stage-0 regs + in2 stage-0 -> buf0 ---------------
    float4 curA[CB];
#pragma unroll
    for (int ch = 0; ch < CB; ++ch)
        curA[ch] = *(const float4*)(b1p + ch * HW);
    b1p += CB * HW;   // -> stage 1

    {
        float4 pv[3];
#pragma unroll
        for (int k = 0; k < 3; ++k) {
            if (k < nslots) {
                float4 t = *(const float4*)(b2p + sOff[k]);
                pv[k] = vld[k] ? t : make_float4(0.f, 0.f, 0.f, 0.f);
            }
        }
#pragma unroll
        for (int k = 0; k < 3; ++k)
            if (k < nslots) *(float4*)(&lds2[0][0] + lOff[k]) = pv[k];
        b2p += CB * HW;   // -> stage 1
        __syncthreads();
    }

    // ---- main loop -------------------------------------------------------
    int cur = 0;
    for (int st = 0; st < NST; ++st) {
        const bool pf = (st + 1 < NST);

        // prefetch next in2 stage into regs (latency hides under compute)
        float4 pv[3];
        if (pf) {
#pragma unroll
            for (int k = 0; k < 3; ++k) {
                if (k < nslots) {
                    float4 t = *(const float4*)(b2p + sOff[k]);
                    pv[k] = vld[k] ? t : make_float4(0.f, 0.f, 0.f, 0.f);
                }
            }
        }

        const float* L2 = lds2[cur];
#pragma unroll
        for (int ch = 0; ch < CB; ++ch) {
            const float4 w0 = *(const float4*)&L2[ch * CH2 + off2];
            const float4 w1 = *(const float4*)&L2[ch * CH2 + off2 + 4];
            const float4 w2 = *(const float4*)&L2[ch * CH2 + off2 + 8];
            const float4 av = curA[ch];
            const float w[12] = {w0.x, w0.y, w0.z, w0.w,
                                 w1.x, w1.y, w1.z, w1.w,
                                 w2.x, w2.y, w2.z, w2.w};
            const float a[4] = {av.x, av.y, av.z, av.w};
#pragma unroll
            for (int dx = 0; dx < 9; ++dx)
#pragma unroll
                for (int p = 0; p < 4; ++p)
                    acc[dx][p] = fmaf(a[p], w[dx + p], acc[dx][p]);
            // refill this reg with NEXT stage's in1 (used next iteration)
            if (pf) curA[ch] = *(const float4*)(b1p + ch * HW);
        }
        b1p += CB * HW;

        if (pf) {
            float* D = &lds2[0][0] + (cur ^ 1) * BUF2;
#pragma unroll
            for (int k = 0; k < 3; ++k)
                if (k < nslots) *(float4*)(D + lOff[k]) = pv[k];
            b2p += CB * HW;
        }
        __syncthreads();
        cur ^= 1;
    }

    // ---- epilogue: direct coalesced stores (no atomics) ------------------
    const float sc = 1.0f / (float)CC;
    float* op = out + ((long)n * 81 + dyI * 9) * HW + (y0 + yy) * WW + x0 + 4 * xg;
#pragma unroll
    for (int dx = 0; dx < 9; ++dx) {
        float4 v;
        v.x = acc[dx][0] * sc;
        v.y = acc[dx][1] * sc;
        v.z = acc[dx][2] * sc;
        v.w = acc[dx][3] * sc;
        *(float4*)(op + (long)dx * HW) = v;
    }
}

extern "C" void kernel_launch(void* const* d_in, const int* in_sizes, int n_in,
                              void* d_out, int out_size, void* d_ws, size_t ws_size,
                              hipStream_t stream) {
    const float* in1 = (const float*)d_in[0];
    const float* in2 = (const float*)d_in[1];
    float* out = (float*)d_out;
    corr_cost_volume<<<dim3(256), dim3(NT), 0, stream>>>(in1, in2, out);
}

// Round 5
// 216.742 us; speedup vs baseline: 2.6951x; 2.4297x over previous
//
#include <hip/hip_runtime.h>

// FlowNet-C cost volume: out[n,d,y,x] = (1/C) * sum_c in1[n,c,y,x]*in2pad[n,c,y+dy,x+dx]
// N=8 C=256 H=64 W=128, d = (dy+4)*9+(dx+4), 81 channels. fp32.
//
// Round 5. Evidence so far: rounds 1/3 both compiled to VGPR=84 (=512/6; the
// register budget appears thread-capacity-derived: floor(2048/576)=3 blocks x
// 9 waves / 4 EU = 6 waves/EU) while live state was ~110 -> spill -> 800+ MB
// scratch writes dominated (WRITE_SIZE 826 MB vs 21 MB ideal output).
// Fix here: FIT in 84 regs instead of fighting the heuristic:
//  - in2 staged with global_load_lds width=16 (no pv regs, no ds_write);
//    S2=40 makes slot->LDS exactly linear (16B*slot), as the instruction
//    needs (wave-uniform base + lane*16). OOB halo lanes source from a
//    zeroed 1KB region of d_ws. Read-side banks: rows y,y+4 alias 2-way = free.
//  - CB=4 channels/stage (curA 32->16 regs), NST=64 stages.
//  - acc[9][4]=36 regs. Live total ~80.
// Belt-and-braces: __launch_bounds__(576,3) + LDS padded past 80KB so only
// 1 block/CU is possible (grid=256 is 1 block/CU anyway).

#define NN 8
#define CC 256
#define HH 64
#define WW 128
#define HW (HH*WW)        // 8192
#define MD 4
#define TH 8
#define TW 32
#define CB 4              // channels per stage
#define NST (CC/CB)       // 64 stages
#define R2 (TH+2*MD)      // 16 in2 rows
#define S2 40             // in2 LDS row stride (floats), NO pad -> linear slot map
#define CH2 (R2*S2)       // 640 floats per channel
#define BUF2 (CB*CH2)     // 2560 floats per buffer = 10240 B
#define SLOTS (CB*R2*10)  // 640 float4 slots per stage
#define NT 576            // 9 waves; wave w <-> dy index w

// async global->LDS, 16B per lane, dest = wave-uniform base + lane*16
#define GLDS(g, l) __builtin_amdgcn_global_load_lds(                      \
    (const __attribute__((address_space(1))) void*)(g),                   \
    (__attribute__((address_space(3))) void*)(l), 16, 0, 0)

__global__ __launch_bounds__(NT, 3)
void corr_cost_volume(const float* __restrict__ in1,
                      const float* __restrict__ in2,
                      const float* __restrict__ zbuf,
                      float* __restrict__ out)
{
    __shared__ float lds2[2][BUF2];     // 20 KB
    __shared__ float opad[15744];       // 61.5 KB pad -> 83456 B total: 1 block/CU

    const int tid  = threadIdx.x;
    const int dyI  = tid >> 6;          // 0..8 (wave = dy+4)
    const int lane = tid & 63;
    const int yy   = lane >> 3;         // 0..7 row in tile
    const int xg   = lane & 7;          // 0..7 4-px group

    const int b  = blockIdx.x;          // grid = 4*8*8 = 256
    const int xt = b & 3;
    const int yt = (b >> 2) & 7;
    const int n  = b >> 5;
    const int x0 = xt * TW;
    const int y0 = yt * TH;

    // keep opad alive without cost (blockIdx range is opaque to the compiler)
    if ((int)blockIdx.x < 0) { opad[tid] = in1[tid]; out[tid] = opad[tid ^ 1]; }

    // ---- staging slots: q = tid (all), plus q = 576+tid for wave 0 -------
    // slot q: ch=q/160, r=(q%160)/10, s=q%10 -> in2 row y0-4+r, cols x0-4+4s
    // LDS float offset = 4*q exactly (S2=40): wave w DMAs chunk [1024w,1024w+1024)
    const float* sp0; int adv0;
    {
        int ch = tid / 160, rem = tid % 160, r = rem / 10, s = rem - r * 10;
        int gy = y0 - MD + r, gx = x0 - MD + 4 * s;
        bool ok = ((unsigned)gy < HH) && ((unsigned)gx < WW);
        sp0 = ok ? in2 + ((long)(n * CC + ch) * HH + gy) * WW + gx
                 : zbuf + 4 * lane;
        adv0 = ok ? CB * HW : 0;
    }
    const float* sp1 = zbuf; int adv1 = 0;
    if (tid < 64) {
        int q = NT + tid;               // 576..639
        int ch = q / 160, rem = q % 160, r = rem / 10, s = rem - r * 10;
        int gy = y0 - MD + r, gx = x0 - MD + 4 * s;
        bool ok = ((unsigned)gy < HH) && ((unsigned)gx < WW);
        sp1 = ok ? in2 + ((long)(n * CC + ch) * HH + gy) * WW + gx
                 : zbuf + 4 * lane;
        adv1 = ok ? CB * HW : 0;
    }
    const int wchunk = (tid >> 6) * 256;   // wave's 1KB LDS chunk (floats)

    const float* b1p = in1 + (long)n * CC * HW + (y0 + yy) * WW + x0 + 4 * xg;
    const int off2 = (yy + dyI) * S2 + 4 * xg;   // in2 window base (16B aligned)

    float acc[9][4];
#pragma unroll
    for (int d = 0; d < 9; ++d)
#pragma unroll
        for (int p = 0; p < 4; ++p) acc[d][p] = 0.0f;

    // ---- prologue: stage 0 -> buf0 (async) + in1 stage-0 regs ------------
    GLDS(sp0, &lds2[0][wchunk]); sp0 += adv0;
    if (tid < 64) { GLDS(sp1, &lds2[0][9 * 256]); sp1 += adv1; }

    float4 curA[CB];
#pragma unroll
    for (int ch = 0; ch < CB; ++ch)
        curA[ch] = *(const float4*)(b1p + ch * HW);
    b1p += CB * HW;
    __syncthreads();    // drains vmcnt -> buf0 ready

    // ---- main loop -------------------------------------------------------
    int cur = 0;
    for (int st = 0; st < NST; ++st) {
        const bool pf = (st + 1 < NST);
        const int nxt = cur ^ 1;

        if (pf) {       // issue next stage's DMA first; lands during compute
            GLDS(sp0, &lds2[nxt][wchunk]); sp0 += adv0;
            if (tid < 64) { GLDS(sp1, &lds2[nxt][9 * 256]); sp1 += adv1; }
        }

        const float* L2 = lds2[cur];
#pragma unroll
        for (int ch = 0; ch < CB; ++ch) {
            const float4 w0 = *(const float4*)&L2[ch * CH2 + off2];
            const float4 w1 = *(const float4*)&L2[ch * CH2 + off2 + 4];
            const float4 w2 = *(const float4*)&L2[ch * CH2 + off2 + 8];
            const float4 av = curA[ch];
            const float w[12] = {w0.x, w0.y, w0.z, w0.w,
                                 w1.x, w1.y, w1.z, w1.w,
                                 w2.x, w2.y, w2.z, w2.w};
            const float a[4] = {av.x, av.y, av.z, av.w};
#pragma unroll
            for (int dx = 0; dx < 9; ++dx)
#pragma unroll
                for (int p = 0; p < 4; ++p)
                    acc[dx][p] = fmaf(a[p], w[dx + p], acc[dx][p]);
            if (pf) curA[ch] = *(const float4*)(b1p + ch * HW);  // next stage's in1
        }
        b1p += CB * HW;

        __syncthreads();   // waits vmcnt(0): next-stage DMA + curA complete
        cur = nxt;
    }

    // ---- epilogue: direct coalesced float4 stores ------------------------
    const float sc = 1.0f / (float)CC;
    float* op = out + ((long)n * 81 + dyI * 9) * HW + (y0 + yy) * WW + x0 + 4 * xg;
#pragma unroll
    for (int dx = 0; dx < 9; ++dx) {
        float4 v;
        v.x = acc[dx][0] * sc;
        v.y = acc[dx][1] * sc;
        v.z = acc[dx][2] * sc;
        v.w = acc[dx][3] * sc;
        *(float4*)(op + (long)dx * HW) = v;
    }
}

extern "C" void kernel_launch(void* const* d_in, const int* in_sizes, int n_in,
                              void* d_out, int out_size, void* d_ws, size_t ws_size,
                              hipStream_t stream) {
    const float* in1 = (const float*)d_in[0];
    const float* in2 = (const float*)d_in[1];
    float* out = (float*)d_out;
    // zero 4KB of workspace: source for out-of-image halo lanes (capture-safe)
    size_t zn = ws_size < 4096 ? ws_size : 4096;
    hipMemsetAsync(d_ws, 0, zn, stream);
    corr_cost_volume<<<dim3(256), dim3(NT), 0, stream>>>(
        in1, in2, (const float*)d_ws, out);
}